// Round 13
// baseline (242.178 us; speedup 1.0000x reference)
//
#include <hip/hip_runtime.h>

#define N_NODES 100000
#define N_EDGES 1600000
#define NBUCK 196            // ceil(N / 512)
#define G1B 3125             // gemm1 blocks (N/32)
#define FB 391               // F2 blocks (x 4096 edges)
#define FEDGE 4096
#define BCAP 9216            // per-bucket capacity: mean 8192, sigma~90 -> 11 sigma

// ---------------- bf16 helpers ----------------
__device__ __forceinline__ unsigned pack_bf16(float a, float b){
  unsigned ua = __float_as_uint(a), ub = __float_as_uint(b);
  ua = ua + 0x7fffu + ((ua >> 16) & 1u);          // RNE
  ub = ub + 0x7fffu + ((ub >> 16) & 1u);
  return (ua >> 16) | (ub & 0xffff0000u);
}
__device__ __forceinline__ unsigned short bf16_of(float a){
  unsigned ua = __float_as_uint(a);
  ua = ua + 0x7fffu + ((ua >> 16) & 1u);
  return (unsigned short)(ua >> 16);
}
__device__ __forceinline__ float bf_lo(unsigned u){ return __uint_as_float(u << 16); }
__device__ __forceinline__ float bf_hi(unsigned u){ return __uint_as_float(u & 0xffff0000u); }

// ---------------- threefry2x32 (JAX partitionable) dropout mask ------------
__device__ __forceinline__ unsigned tf_rotl(unsigned x, int r){ return (x<<r)|(x>>(32-r)); }

__device__ __forceinline__ unsigned dropout_keep(unsigned e){
  unsigned x0 = 0u, x1 = e;
  const unsigned k0 = 0u, k1v = 42u;
  const unsigned k2 = 0x1BD11BDAu ^ k0 ^ k1v;
#define TF_R(r) { x0 += x1; x1 = tf_rotl(x1,(r)); x1 ^= x0; }
  x0 += k0; x1 += k1v;
  TF_R(13) TF_R(15) TF_R(26) TF_R(6)
  x0 += k1v; x1 += k2 + 1u;
  TF_R(17) TF_R(29) TF_R(16) TF_R(24)
  x0 += k2; x1 += k0 + 2u;
  TF_R(13) TF_R(15) TF_R(26) TF_R(6)
  x0 += k0; x1 += k1v + 3u;
  TF_R(17) TF_R(29) TF_R(16) TF_R(24)
  x0 += k1v; x1 += k2 + 4u;
  TF_R(13) TF_R(15) TF_R(26) TF_R(6)
  x0 += k2; x1 += k0 + 5u;
#undef TF_R
  return (x0 ^ x1) >> 31;
}

// ---------------- gemm1 tile ------------------------------------------------
// h1g[N][64] u32 of bf16 pairs = x @ W1. 32KB LDS: x-tile + W1 quarter.
__device__ __forceinline__ void gemm1_block(int gb, int t, float* smem,
                                            const float* __restrict__ x,
                                            const float* __restrict__ W1,
                                            unsigned* __restrict__ h1g){
  float* xs = smem;            // [32][128]
  float* Wq = smem + 4096;     // [32][128] quarter of W1
  size_t row0 = (size_t)gb * 32;

  const float4* xv = (const float4*)(x + row0*128);
  float4* xsv = (float4*)xs;
  #pragma unroll
  for (int j = 0; j < 4; j++) xsv[t + 256*j] = xv[t + 256*j];

  int tx = t & 31, ty = t >> 5;
  float acc[4][4] = {};
  const float4* Wv = (const float4*)W1;
  float4* Wqv = (float4*)Wq;
  const float* xr = xs + (ty*4)*128;

  for (int q = 0; q < 4; q++){
    __syncthreads();
    #pragma unroll
    for (int j = 0; j < 4; j++) Wqv[t + 256*j] = Wv[q*1024 + t + 256*j];
    __syncthreads();
    int kbase = q*32;
    #pragma unroll 8
    for (int kk = 0; kk < 32; kk++){
      float4 w = *(const float4*)(Wq + kk*128 + tx*4);
      int k = kbase + kk;
      float x0 = xr[k], x1 = xr[128 + k], x2 = xr[256 + k], x3 = xr[384 + k];
      acc[0][0] = fmaf(x0, w.x, acc[0][0]); acc[0][1] = fmaf(x0, w.y, acc[0][1]);
      acc[0][2] = fmaf(x0, w.z, acc[0][2]); acc[0][3] = fmaf(x0, w.w, acc[0][3]);
      acc[1][0] = fmaf(x1, w.x, acc[1][0]); acc[1][1] = fmaf(x1, w.y, acc[1][1]);
      acc[1][2] = fmaf(x1, w.z, acc[1][2]); acc[1][3] = fmaf(x1, w.w, acc[1][3]);
      acc[2][0] = fmaf(x2, w.x, acc[2][0]); acc[2][1] = fmaf(x2, w.y, acc[2][1]);
      acc[2][2] = fmaf(x2, w.z, acc[2][2]); acc[2][3] = fmaf(x2, w.w, acc[2][3]);
      acc[3][0] = fmaf(x3, w.x, acc[3][0]); acc[3][1] = fmaf(x3, w.y, acc[3][1]);
      acc[3][2] = fmaf(x3, w.z, acc[3][2]); acc[3][3] = fmaf(x3, w.w, acc[3][3]);
    }
  }
  #pragma unroll
  for (int i = 0; i < 4; i++){
    uint2 o;
    o.x = pack_bf16(acc[i][0], acc[i][1]);
    o.y = pack_bf16(acc[i][2], acc[i][3]);
    *(uint2*)(h1g + (row0 + ty*4 + i)*64 + tx*2) = o;
  }
}

// ---------------- k_B: F2 bucket-append (fixed regions, AoS) + ALL gemm1 ----
// F2: 391 blocks x 4096 edges (tail balance); AoS int2 tmp = ONE scatter
// stream per bucket run (SoA doubled partial-line evictions in R12).
__launch_bounds__(256)
__global__ void k_B(const float* __restrict__ x, const float* __restrict__ W1,
                    unsigned* __restrict__ h1g,
                    const int* __restrict__ src, const int* __restrict__ dst,
                    int* __restrict__ bcur2, int2* __restrict__ tmp, int N, int E){
  extern __shared__ float smem[];
  int t = threadIdx.x;
  if (blockIdx.x < FB){
    int* hist = (int*)smem;                 // [NBUCK]
    int fb = blockIdx.x;
    for (int i = t; i < NBUCK; i += 256) hist[i] = 0;
    __syncthreads();
    int e0 = fb*FEDGE;
    #pragma unroll 4
    for (int j = 0; j < FEDGE/256; j++){
      int e = e0 + t + j*256;
      if (e < E) atomicAdd(&hist[dst[e] >> 9], 1);
    }
    __syncthreads();
    if (t < NBUCK){
      int c = hist[t];
      if (c > 0) hist[t] = t*BCAP + atomicAdd(&bcur2[t], c);
    }
    __syncthreads();
    #pragma unroll 4
    for (int j = 0; j < FEDGE/256; j++){
      int e = e0 + t + j*256;
      if (e < E){
        int d = dst[e], s = src[e];
        int p = atomicAdd(&hist[d >> 9], 1);
        tmp[p] = make_int2(s, d);
      }
    }
    return;
  }
  int gb = blockIdx.x - FB;
  if (gb < G1B) gemm1_block(gb, t, smem, x, W1, h1g);
}

// ---------------- k_hist: per-bucket degree histogram + local prefix --------
__launch_bounds__(512)
__global__ void k_hist(const int2* __restrict__ tmp, const int* __restrict__ bcur2,
                       int* __restrict__ degi, int* __restrict__ off,
                       float* __restrict__ dii, int N){
  __shared__ int cur[512];
  __shared__ int wtot[8];
  int b = blockIdx.x, t = threadIdx.x;
  cur[t] = 0;
  __syncthreads();
  int m = bcur2[b];
  int base = b*BCAP;
  int node0 = b << 9;
  for (int i = t; i < m; i += 512)
    atomicAdd(&cur[tmp[base + i].y - node0], 1);
  __syncthreads();
  int v = cur[t];
  int lane = t & 63, w = t >> 6;
  int incl = v;
  for (int d = 1; d < 64; d <<= 1){
    int y = __shfl_up(incl, d);
    if (lane >= d) incl += y;
  }
  if (lane == 63) wtot[w] = incl;
  __syncthreads();
  int wb = 0;
  for (int i = 0; i < w; i++) wb += wtot[i];
  int excl = wb + incl - v;
  int n = node0 + t;
  if (n < N){
    degi[n] = v;
    off[n]  = base + excl;
    dii[n]  = rsqrtf((float)(v + 1));
  }
}

// ---------------- k_csort: per-bucket counting sort into final CSR ----------
__launch_bounds__(1024)
__global__ void k_csort(const int2* __restrict__ tmp, int2* __restrict__ csre,
                        const int* __restrict__ off, const int* __restrict__ bcur2,
                        const float* __restrict__ dii, int N){
  __shared__ int   cur[512];
  __shared__ float dl[512];
  int b = blockIdx.x, t = threadIdx.x;
  int node0 = b << 9;
  if (t < 512){
    int n = node0 + t;
    cur[t] = (n < N) ? off[n] : 0;
    dl[t]  = (n < N) ? dii[n] : 0.f;
  }
  __syncthreads();
  int m = bcur2[b];
  int base = b*BCAP;
  for (int i = t; i < m; i += 1024){
    int2 r = tmp[base + i];
    int dloc = r.y - node0;
    float w = dii[r.x] * dl[dloc];
    int p = atomicAdd(&cur[dloc], 1);
    csre[p] = make_int2(r.x, __float_as_int(w));
  }
}

// ---------------- agg1: Bbg(bf16) = dropout(relu(segsum(h1[src]*w)+b1)) -----
__launch_bounds__(256)
__global__ void k_agg1(const unsigned* __restrict__ h1g, unsigned* __restrict__ Bbg,
                       const int2* __restrict__ csre, const int* __restrict__ off,
                       const int* __restrict__ degi, const float* __restrict__ dii,
                       const float* __restrict__ b1, int N){
  int n = blockIdx.x*4 + (threadIdx.x >> 6);
  int lane = threadIdx.x & 63;
  if (n >= N) return;
  n = __builtin_amdgcn_readfirstlane(n);
  float din = dii[n];
  float s2 = din*din;
  unsigned su = h1g[(size_t)n*64 + lane];
  float a0 = bf_lo(su)*s2, a1 = bf_hi(su)*s2;
  int o = off[n], cnt = degi[n];
  int i = 0;
  for (; i + 8 <= cnt; i += 8){
    int2 e0 = csre[o+i+0], e1 = csre[o+i+1], e2 = csre[o+i+2], e3 = csre[o+i+3];
    int2 e4 = csre[o+i+4], e5 = csre[o+i+5], e6 = csre[o+i+6], e7 = csre[o+i+7];
    unsigned u0 = h1g[(size_t)e0.x*64 + lane];
    unsigned u1 = h1g[(size_t)e1.x*64 + lane];
    unsigned u2 = h1g[(size_t)e2.x*64 + lane];
    unsigned u3 = h1g[(size_t)e3.x*64 + lane];
    unsigned u4 = h1g[(size_t)e4.x*64 + lane];
    unsigned u5 = h1g[(size_t)e5.x*64 + lane];
    unsigned u6 = h1g[(size_t)e6.x*64 + lane];
    unsigned u7 = h1g[(size_t)e7.x*64 + lane];
    float w0 = __int_as_float(e0.y), w1 = __int_as_float(e1.y);
    float w2 = __int_as_float(e2.y), w3 = __int_as_float(e3.y);
    float w4 = __int_as_float(e4.y), w5 = __int_as_float(e5.y);
    float w6 = __int_as_float(e6.y), w7 = __int_as_float(e7.y);
    a0 = fmaf(bf_lo(u0), w0, a0); a1 = fmaf(bf_hi(u0), w0, a1);
    a0 = fmaf(bf_lo(u1), w1, a0); a1 = fmaf(bf_hi(u1), w1, a1);
    a0 = fmaf(bf_lo(u2), w2, a0); a1 = fmaf(bf_hi(u2), w2, a1);
    a0 = fmaf(bf_lo(u3), w3, a0); a1 = fmaf(bf_hi(u3), w3, a1);
    a0 = fmaf(bf_lo(u4), w4, a0); a1 = fmaf(bf_hi(u4), w4, a1);
    a0 = fmaf(bf_lo(u5), w5, a0); a1 = fmaf(bf_hi(u5), w5, a1);
    a0 = fmaf(bf_lo(u6), w6, a0); a1 = fmaf(bf_hi(u6), w6, a1);
    a0 = fmaf(bf_lo(u7), w7, a0); a1 = fmaf(bf_hi(u7), w7, a1);
  }
  for (; i < cnt; ++i){
    int2 e = csre[o+i];
    unsigned u = h1g[(size_t)e.x*64 + lane];
    float w = __int_as_float(e.y);
    a0 = fmaf(bf_lo(u), w, a0); a1 = fmaf(bf_hi(u), w, a1);
  }
  float2 bb = *(const float2*)(b1 + lane*2);
  a0 = fmaxf(a0 + bb.x, 0.f);
  a1 = fmaxf(a1 + bb.y, 0.f);
  unsigned e0i = (unsigned)n*128u + (unsigned)lane*2u;
  a0 = dropout_keep(e0i)      ? a0*2.f : 0.f;
  a1 = dropout_keep(e0i + 1u) ? a1*2.f : 0.f;
  Bbg[(size_t)n*64 + lane] = pack_bf16(a0, a1);
}

// ---------------- GEMM2: h2p(bf16, padded rows) = B @ W2 --------------------
// h2p[N][64] ushorts, cols 0..39 valid; padding lets agg2 use agg1's shape.
__launch_bounds__(256)
__global__ void k_gemm2(const unsigned* __restrict__ Bbg, const float* __restrict__ W2,
                        unsigned short* __restrict__ h2p, int N){
  __shared__ float W2T[40*132];
  __shared__ float Bs[64*132];
  int t = threadIdx.x;
  int row0 = blockIdx.x * 64;
  for (int idx = t; idx < 128*40; idx += 256){
    int r = idx / 40, c = idx - 40*r;
    W2T[c*132 + r] = W2[idx];
  }
  #pragma unroll
  for (int j = 0; j < 8; j++){
    int idx = t + 256*j;            // uint2 units: 64 rows x 32
    int r = idx >> 5, c2 = idx & 31;
    int gr = row0 + r; if (gr > N-1) gr = N-1;
    uint2 v = *(const uint2*)(Bbg + (size_t)gr*64 + c2*2);
    float4 f = { bf_lo(v.x), bf_hi(v.x), bf_lo(v.y), bf_hi(v.y) };
    *(float4*)(Bs + r*132 + c2*4) = f;
  }
  __syncthreads();

  int cg = t & 7, rg = t >> 3;
  int c0 = cg*5, r0 = rg*2;
  float acc[2][5] = {};
  #pragma unroll 4
  for (int k = 0; k < 128; k++){
    float bv0 = Bs[r0*132 + k], bv1 = Bs[(r0+1)*132 + k];
    #pragma unroll
    for (int u = 0; u < 5; u++){
      float w = W2T[(c0+u)*132 + k];
      acc[0][u] = fmaf(bv0, w, acc[0][u]);
      acc[1][u] = fmaf(bv1, w, acc[1][u]);
    }
  }
  #pragma unroll
  for (int i = 0; i < 2; i++){
    int gr = row0 + r0 + i;
    if (gr < N){
      #pragma unroll
      for (int u = 0; u < 5; u++) h2p[(size_t)gr*64 + c0 + u] = bf16_of(acc[i][u]);
    }
  }
}

// ---------------- agg2: out = segsum(h2[src]*w) + b2 ------------------------
// agg1's proven shape on padded [N][32]-u32 rows: all 64 lanes gather at
// s*32 + (lane&31) (upper half duplicates lower -> VMEM merges, no cndmask);
// scalar edge records; 8-edge unroll; lanes 0..19 write float2.
__launch_bounds__(256)
__global__ void k_agg2(const unsigned* __restrict__ h2p, float* __restrict__ out,
                       const int2* __restrict__ csre, const int* __restrict__ off,
                       const int* __restrict__ degi, const float* __restrict__ dii,
                       const float* __restrict__ b2, int N){
  int n = blockIdx.x*4 + (threadIdx.x >> 6);
  int lane31 = threadIdx.x & 31;
  int lane   = threadIdx.x & 63;
  if (n >= N) return;
  n = __builtin_amdgcn_readfirstlane(n);
  float din = dii[n];
  float s2 = din*din;
  unsigned su = h2p[(size_t)n*32 + lane31];
  float a0 = bf_lo(su)*s2, a1 = bf_hi(su)*s2;
  int o = off[n], cnt = degi[n];
  int i = 0;
  for (; i + 8 <= cnt; i += 8){
    int2 e0 = csre[o+i+0], e1 = csre[o+i+1], e2 = csre[o+i+2], e3 = csre[o+i+3];
    int2 e4 = csre[o+i+4], e5 = csre[o+i+5], e6 = csre[o+i+6], e7 = csre[o+i+7];
    unsigned u0 = h2p[(size_t)e0.x*32 + lane31];
    unsigned u1 = h2p[(size_t)e1.x*32 + lane31];
    unsigned u2 = h2p[(size_t)e2.x*32 + lane31];
    unsigned u3 = h2p[(size_t)e3.x*32 + lane31];
    unsigned u4 = h2p[(size_t)e4.x*32 + lane31];
    unsigned u5 = h2p[(size_t)e5.x*32 + lane31];
    unsigned u6 = h2p[(size_t)e6.x*32 + lane31];
    unsigned u7 = h2p[(size_t)e7.x*32 + lane31];
    float w0 = __int_as_float(e0.y), w1 = __int_as_float(e1.y);
    float w2 = __int_as_float(e2.y), w3 = __int_as_float(e3.y);
    float w4 = __int_as_float(e4.y), w5 = __int_as_float(e5.y);
    float w6 = __int_as_float(e6.y), w7 = __int_as_float(e7.y);
    a0 = fmaf(bf_lo(u0), w0, a0); a1 = fmaf(bf_hi(u0), w0, a1);
    a0 = fmaf(bf_lo(u1), w1, a0); a1 = fmaf(bf_hi(u1), w1, a1);
    a0 = fmaf(bf_lo(u2), w2, a0); a1 = fmaf(bf_hi(u2), w2, a1);
    a0 = fmaf(bf_lo(u3), w3, a0); a1 = fmaf(bf_hi(u3), w3, a1);
    a0 = fmaf(bf_lo(u4), w4, a0); a1 = fmaf(bf_hi(u4), w4, a1);
    a0 = fmaf(bf_lo(u5), w5, a0); a1 = fmaf(bf_hi(u5), w5, a1);
    a0 = fmaf(bf_lo(u6), w6, a0); a1 = fmaf(bf_hi(u6), w6, a1);
    a0 = fmaf(bf_lo(u7), w7, a0); a1 = fmaf(bf_hi(u7), w7, a1);
  }
  for (; i < cnt; ++i){
    int2 e = csre[o+i];
    unsigned u = h2p[(size_t)e.x*32 + lane31];
    float w = __int_as_float(e.y);
    a0 = fmaf(bf_lo(u), w, a0); a1 = fmaf(bf_hi(u), w, a1);
  }
  if (lane < 20){
    float2 bb = *(const float2*)(b2 + lane*2);
    a0 += bb.x;
    a1 += bb.y;
    *(float2*)(out + (size_t)n*40 + lane*2) = make_float2(a0, a1);
  }
}

// ---------------- launch ----------------
extern "C" void kernel_launch(void* const* d_in, const int* in_sizes, int n_in,
                              void* d_out, int out_size, void* d_ws, size_t ws_size,
                              hipStream_t stream){
  const float* x  = (const float*)d_in[0];
  const int*   ei = (const int*)  d_in[1];
  const float* W1 = (const float*)d_in[2];
  const float* b1 = (const float*)d_in[3];
  const float* W2 = (const float*)d_in[4];
  const float* b2 = (const float*)d_in[5];
  float* out = (float*)d_out;
  char* ws = (char*)d_ws;
  const int N = N_NODES, E = N_EDGES;
  const int* srcv = ei;
  const int* dstv = ei + E;

  // workspace layout (bytes); total ~81.3 MB
  int*   bcur2 = (int*)  (ws + 0);          // 196 ints (zeroed each call)
  int*   off   = (int*)  (ws + 8192);       // N ints
  int*   degi  = (int*)  (ws + 417792);     // N ints
  float* dii   = (float*)(ws + 827392);     // N floats
  int2*  tmp   = (int2*) (ws + 1236992);    // 196*9216 int2 (14.45 MB)
  int2*  csre  = (int2*) (ws + 15687680);   // 196*9216 int2 (14.45 MB)
  unsigned*       h1g = (unsigned*)      (ws + 30138368);  // [N][64] u32 = 25.6 MB
  unsigned short* h2p = (unsigned short*)(ws + 30138368);  // [N][64] u16 = 12.8 MB, aliases dead h1g
  unsigned*       Bbg = (unsigned*)      (ws + 55738368);  // [N][64] u32 = 25.6 MB

  hipMemsetAsync(bcur2, 0, 8192, stream);

  // k_B: F2 append (fixed bucket regions) + ALL gemm1 blocks
  k_B<<<FB + G1B, 256, 32768, stream>>>(x, W1, h1g, srcv, dstv, bcur2, tmp, N, E);
  // degree histogram + prefix
  k_hist<<<NBUCK, 512, 0, stream>>>(tmp, bcur2, degi, off, dii, N);
  // counting sort -> final CSR
  k_csort<<<NBUCK, 1024, 0, stream>>>(tmp, csre, off, bcur2, dii, N);

  k_agg1 <<<N/4, 256, 0, stream>>>(h1g, Bbg, csre, off, degi, dii, b1, N);
  k_gemm2<<<(N + 63)/64, 256, 0, stream>>>(Bbg, W2, h2p, N);
  k_agg2 <<<N/4, 256, 0, stream>>>((const unsigned*)h2p, out, csre, off, degi, dii, b2, N);
}

// Round 14
// 229.721 us; speedup vs baseline: 1.0542x; 1.0542x over previous
//
#include <hip/hip_runtime.h>

#define N_NODES 100000
#define N_EDGES 1600000
#define NBUCK 196            // ceil(N / 512)
#define G1B 1563             // gemm1 blocks (64 rows each)
#define FB 391               // F2 blocks (x 4096 edges)
#define FEDGE 4096
#define BCAP 9216            // per-bucket capacity: mean 8192, sigma~90 -> 11 sigma

typedef __attribute__((ext_vector_type(8))) short short8v;   // 8 bf16 (4 VGPRs)
typedef __attribute__((ext_vector_type(4))) float f32x4;

// ---------------- bf16 helpers ----------------
__device__ __forceinline__ unsigned pack_bf16(float a, float b){
  unsigned ua = __float_as_uint(a), ub = __float_as_uint(b);
  ua = ua + 0x7fffu + ((ua >> 16) & 1u);          // RNE
  ub = ub + 0x7fffu + ((ub >> 16) & 1u);
  return (ua >> 16) | (ub & 0xffff0000u);
}
__device__ __forceinline__ unsigned short bf16_of(float a){
  unsigned ua = __float_as_uint(a);
  ua = ua + 0x7fffu + ((ua >> 16) & 1u);
  return (unsigned short)(ua >> 16);
}
__device__ __forceinline__ float bf_lo(unsigned u){ return __uint_as_float(u << 16); }
__device__ __forceinline__ float bf_hi(unsigned u){ return __uint_as_float(u & 0xffff0000u); }

// ---------------- threefry2x32 (JAX partitionable) dropout mask ------------
__device__ __forceinline__ unsigned tf_rotl(unsigned x, int r){ return (x<<r)|(x>>(32-r)); }

__device__ __forceinline__ unsigned dropout_keep(unsigned e){
  unsigned x0 = 0u, x1 = e;
  const unsigned k0 = 0u, k1v = 42u;
  const unsigned k2 = 0x1BD11BDAu ^ k0 ^ k1v;
#define TF_R(r) { x0 += x1; x1 = tf_rotl(x1,(r)); x1 ^= x0; }
  x0 += k0; x1 += k1v;
  TF_R(13) TF_R(15) TF_R(26) TF_R(6)
  x0 += k1v; x1 += k2 + 1u;
  TF_R(17) TF_R(29) TF_R(16) TF_R(24)
  x0 += k2; x1 += k0 + 2u;
  TF_R(13) TF_R(15) TF_R(26) TF_R(6)
  x0 += k0; x1 += k1v + 3u;
  TF_R(17) TF_R(29) TF_R(16) TF_R(24)
  x0 += k1v; x1 += k2 + 4u;
  TF_R(13) TF_R(15) TF_R(26) TF_R(6)
  x0 += k2; x1 += k0 + 5u;
#undef TF_R
  return (x0 ^ x1) >> 31;
}

// ---------------- k_wt: W1T[n][k] = bf16(W1[k][n])  (32KB, L2-broadcast) ----
__global__ void k_wt(const float* __restrict__ W1, unsigned short* __restrict__ W1T){
  int idx = blockIdx.x*256 + threadIdx.x;      // 64 blocks x 256 = 16384
  int k = idx >> 7, n = idx & 127;
  W1T[n*128 + k] = bf16_of(W1[idx]);
}

// ---------------- k_B: F2 bucket-append + MFMA gemm1 ------------------------
// F2: 391 blocks x 4096 edges -> bucket-contiguous (src,dst) runs.
// gemm: 1563 blocks x 64 rows, bf16 MFMA (16x16x32), NO LDS: A-frags are
// converted inline from global x (each wave owns 16 distinct rows -> x read
// once); B-frags are 16B contiguous loads from L2-resident W1T.
// Layouts: A lane l supplies row (l&15), k = 8*(l>>4)+j (contiguous 8);
// B: col (l&15), same k; C/D: col=l&15, row=(l>>4)*4+reg [guide-verified].
__launch_bounds__(256)
__global__ void k_B(const float* __restrict__ x, const unsigned short* __restrict__ W1T,
                    unsigned short* __restrict__ h1u,
                    const int* __restrict__ src, const int* __restrict__ dst,
                    int* __restrict__ bcur2, int2* __restrict__ tmp, int N, int E){
  __shared__ int hist[NBUCK];
  int t = threadIdx.x;
  if (blockIdx.x < FB){
    int fb = blockIdx.x;
    for (int i = t; i < NBUCK; i += 256) hist[i] = 0;
    __syncthreads();
    int e0 = fb*FEDGE;
    #pragma unroll 4
    for (int j = 0; j < FEDGE/256; j++){
      int e = e0 + t + j*256;
      if (e < E) atomicAdd(&hist[dst[e] >> 9], 1);
    }
    __syncthreads();
    if (t < NBUCK){
      int c = hist[t];
      if (c > 0) hist[t] = t*BCAP + atomicAdd(&bcur2[t], c);
    }
    __syncthreads();
    #pragma unroll 4
    for (int j = 0; j < FEDGE/256; j++){
      int e = e0 + t + j*256;
      if (e < E){
        int d = dst[e], s = src[e];
        int p = atomicAdd(&hist[d >> 9], 1);
        tmp[p] = make_int2(s, d);
      }
    }
    return;
  }
  // ---------- MFMA gemm role ----------
  int gb = blockIdx.x - FB;
  if (gb >= G1B) return;
  int w = t >> 6, l = t & 63;
  int lo = l & 15, hi = l >> 4;
  int rowA = gb*64 + w*16 + lo;
  int rA = (rowA < N) ? rowA : (N-1);
  const float4* xr = (const float4*)(x + (size_t)rA*128);

  short8v a[4];
  #pragma unroll
  for (int kk = 0; kk < 4; kk++){
    float4 f0 = xr[kk*8 + 2*hi];
    float4 f1 = xr[kk*8 + 2*hi + 1];
    union { short8v v; unsigned u[4]; } A;
    A.u[0] = pack_bf16(f0.x, f0.y);
    A.u[1] = pack_bf16(f0.z, f0.w);
    A.u[2] = pack_bf16(f1.x, f1.y);
    A.u[3] = pack_bf16(f1.z, f1.w);
    a[kk] = A.v;
  }
  int rowC0 = gb*64 + w*16 + hi*4;
  #pragma unroll
  for (int tt = 0; tt < 8; tt++){
    int n0 = tt*16;
    const uint4* brow = (const uint4*)(W1T + (n0 + lo)*128);
    f32x4 acc = {0.f, 0.f, 0.f, 0.f};
    #pragma unroll
    for (int kk = 0; kk < 4; kk++){
      union { short8v v; uint4 q; } B;
      B.q = brow[kk*4 + hi];
      acc = __builtin_amdgcn_mfma_f32_16x16x32_bf16(a[kk], B.v, acc, 0, 0, 0);
    }
    int colC = n0 + lo;
    #pragma unroll
    for (int r = 0; r < 4; r++){
      int rc = rowC0 + r;
      if (rc < N) h1u[(size_t)rc*128 + colC] = bf16_of(acc[r]);
    }
  }
}

// ---------------- k_hist: per-bucket degree histogram + local prefix --------
__launch_bounds__(512)
__global__ void k_hist(const int2* __restrict__ tmp, const int* __restrict__ bcur2,
                       int* __restrict__ degi, int* __restrict__ off,
                       float* __restrict__ dii, int N){
  __shared__ int cur[512];
  __shared__ int wtot[8];
  int b = blockIdx.x, t = threadIdx.x;
  cur[t] = 0;
  __syncthreads();
  int m = bcur2[b];
  int base = b*BCAP;
  int node0 = b << 9;
  for (int i = t; i < m; i += 512)
    atomicAdd(&cur[tmp[base + i].y - node0], 1);
  __syncthreads();
  int v = cur[t];
  int lane = t & 63, w = t >> 6;
  int incl = v;
  for (int d = 1; d < 64; d <<= 1){
    int y = __shfl_up(incl, d);
    if (lane >= d) incl += y;
  }
  if (lane == 63) wtot[w] = incl;
  __syncthreads();
  int wb = 0;
  for (int i = 0; i < w; i++) wb += wtot[i];
  int excl = wb + incl - v;
  int n = node0 + t;
  if (n < N){
    degi[n] = v;
    off[n]  = base + excl;
    dii[n]  = rsqrtf((float)(v + 1));
  }
}

// ---------------- k_csort: per-bucket counting sort into final CSR ----------
__launch_bounds__(1024)
__global__ void k_csort(const int2* __restrict__ tmp, int2* __restrict__ csre,
                        const int* __restrict__ off, const int* __restrict__ bcur2,
                        const float* __restrict__ dii, int N){
  __shared__ int   cur[512];
  __shared__ float dl[512];
  int b = blockIdx.x, t = threadIdx.x;
  int node0 = b << 9;
  if (t < 512){
    int n = node0 + t;
    cur[t] = (n < N) ? off[n] : 0;
    dl[t]  = (n < N) ? dii[n] : 0.f;
  }
  __syncthreads();
  int m = bcur2[b];
  int base = b*BCAP;
  for (int i = t; i < m; i += 1024){
    int2 r = tmp[base + i];
    int dloc = r.y - node0;
    float w = dii[r.x] * dl[dloc];
    int p = atomicAdd(&cur[dloc], 1);
    csre[p] = make_int2(r.x, __float_as_int(w));
  }
}

// ---------------- agg1: Bbg(bf16) = dropout(relu(segsum(h1[src]*w)+b1)) -----
__launch_bounds__(256)
__global__ void k_agg1(const unsigned* __restrict__ h1g, unsigned* __restrict__ Bbg,
                       const int2* __restrict__ csre, const int* __restrict__ off,
                       const int* __restrict__ degi, const float* __restrict__ dii,
                       const float* __restrict__ b1, int N){
  int n = blockIdx.x*4 + (threadIdx.x >> 6);
  int lane = threadIdx.x & 63;
  if (n >= N) return;
  n = __builtin_amdgcn_readfirstlane(n);
  float din = dii[n];
  float s2 = din*din;
  unsigned su = h1g[(size_t)n*64 + lane];
  float a0 = bf_lo(su)*s2, a1 = bf_hi(su)*s2;
  int o = off[n], cnt = degi[n];
  int i = 0;
  for (; i + 8 <= cnt; i += 8){
    int2 e0 = csre[o+i+0], e1 = csre[o+i+1], e2 = csre[o+i+2], e3 = csre[o+i+3];
    int2 e4 = csre[o+i+4], e5 = csre[o+i+5], e6 = csre[o+i+6], e7 = csre[o+i+7];
    unsigned u0 = h1g[(size_t)e0.x*64 + lane];
    unsigned u1 = h1g[(size_t)e1.x*64 + lane];
    unsigned u2 = h1g[(size_t)e2.x*64 + lane];
    unsigned u3 = h1g[(size_t)e3.x*64 + lane];
    unsigned u4 = h1g[(size_t)e4.x*64 + lane];
    unsigned u5 = h1g[(size_t)e5.x*64 + lane];
    unsigned u6 = h1g[(size_t)e6.x*64 + lane];
    unsigned u7 = h1g[(size_t)e7.x*64 + lane];
    float w0 = __int_as_float(e0.y), w1 = __int_as_float(e1.y);
    float w2 = __int_as_float(e2.y), w3 = __int_as_float(e3.y);
    float w4 = __int_as_float(e4.y), w5 = __int_as_float(e5.y);
    float w6 = __int_as_float(e6.y), w7 = __int_as_float(e7.y);
    a0 = fmaf(bf_lo(u0), w0, a0); a1 = fmaf(bf_hi(u0), w0, a1);
    a0 = fmaf(bf_lo(u1), w1, a0); a1 = fmaf(bf_hi(u1), w1, a1);
    a0 = fmaf(bf_lo(u2), w2, a0); a1 = fmaf(bf_hi(u2), w2, a1);
    a0 = fmaf(bf_lo(u3), w3, a0); a1 = fmaf(bf_hi(u3), w3, a1);
    a0 = fmaf(bf_lo(u4), w4, a0); a1 = fmaf(bf_hi(u4), w4, a1);
    a0 = fmaf(bf_lo(u5), w5, a0); a1 = fmaf(bf_hi(u5), w5, a1);
    a0 = fmaf(bf_lo(u6), w6, a0); a1 = fmaf(bf_hi(u6), w6, a1);
    a0 = fmaf(bf_lo(u7), w7, a0); a1 = fmaf(bf_hi(u7), w7, a1);
  }
  for (; i < cnt; ++i){
    int2 e = csre[o+i];
    unsigned u = h1g[(size_t)e.x*64 + lane];
    float w = __int_as_float(e.y);
    a0 = fmaf(bf_lo(u), w, a0); a1 = fmaf(bf_hi(u), w, a1);
  }
  float2 bb = *(const float2*)(b1 + lane*2);
  a0 = fmaxf(a0 + bb.x, 0.f);
  a1 = fmaxf(a1 + bb.y, 0.f);
  unsigned e0i = (unsigned)n*128u + (unsigned)lane*2u;
  a0 = dropout_keep(e0i)      ? a0*2.f : 0.f;
  a1 = dropout_keep(e0i + 1u) ? a1*2.f : 0.f;
  Bbg[(size_t)n*64 + lane] = pack_bf16(a0, a1);
}

// ---------------- GEMM2: h2p(bf16, padded rows) = B @ W2 --------------------
__launch_bounds__(256)
__global__ void k_gemm2(const unsigned* __restrict__ Bbg, const float* __restrict__ W2,
                        unsigned short* __restrict__ h2p, int N){
  __shared__ float W2T[40*132];
  __shared__ float Bs[64*132];
  int t = threadIdx.x;
  int row0 = blockIdx.x * 64;
  for (int idx = t; idx < 128*40; idx += 256){
    int r = idx / 40, c = idx - 40*r;
    W2T[c*132 + r] = W2[idx];
  }
  #pragma unroll
  for (int j = 0; j < 8; j++){
    int idx = t + 256*j;            // uint2 units: 64 rows x 32
    int r = idx >> 5, c2 = idx & 31;
    int gr = row0 + r; if (gr > N-1) gr = N-1;
    uint2 v = *(const uint2*)(Bbg + (size_t)gr*64 + c2*2);
    float4 f = { bf_lo(v.x), bf_hi(v.x), bf_lo(v.y), bf_hi(v.y) };
    *(float4*)(Bs + r*132 + c2*4) = f;
  }
  __syncthreads();

  int cg = t & 7, rg = t >> 3;
  int c0 = cg*5, r0 = rg*2;
  float acc[2][5] = {};
  #pragma unroll 4
  for (int k = 0; k < 128; k++){
    float bv0 = Bs[r0*132 + k], bv1 = Bs[(r0+1)*132 + k];
    #pragma unroll
    for (int u = 0; u < 5; u++){
      float w = W2T[(c0+u)*132 + k];
      acc[0][u] = fmaf(bv0, w, acc[0][u]);
      acc[1][u] = fmaf(bv1, w, acc[1][u]);
    }
  }
  #pragma unroll
  for (int i = 0; i < 2; i++){
    int gr = row0 + r0 + i;
    if (gr < N){
      #pragma unroll
      for (int u = 0; u < 5; u++) h2p[(size_t)gr*64 + c0 + u] = bf16_of(acc[i][u]);
    }
  }
}

// ---------------- agg2: out = segsum(h2[src]*w) + b2 ------------------------
__launch_bounds__(256)
__global__ void k_agg2(const unsigned* __restrict__ h2p, float* __restrict__ out,
                       const int2* __restrict__ csre, const int* __restrict__ off,
                       const int* __restrict__ degi, const float* __restrict__ dii,
                       const float* __restrict__ b2, int N){
  int n = blockIdx.x*4 + (threadIdx.x >> 6);
  int lane31 = threadIdx.x & 31;
  int lane   = threadIdx.x & 63;
  if (n >= N) return;
  n = __builtin_amdgcn_readfirstlane(n);
  float din = dii[n];
  float s2 = din*din;
  unsigned su = h2p[(size_t)n*32 + lane31];
  float a0 = bf_lo(su)*s2, a1 = bf_hi(su)*s2;
  int o = off[n], cnt = degi[n];
  int i = 0;
  for (; i + 8 <= cnt; i += 8){
    int2 e0 = csre[o+i+0], e1 = csre[o+i+1], e2 = csre[o+i+2], e3 = csre[o+i+3];
    int2 e4 = csre[o+i+4], e5 = csre[o+i+5], e6 = csre[o+i+6], e7 = csre[o+i+7];
    unsigned u0 = h2p[(size_t)e0.x*32 + lane31];
    unsigned u1 = h2p[(size_t)e1.x*32 + lane31];
    unsigned u2 = h2p[(size_t)e2.x*32 + lane31];
    unsigned u3 = h2p[(size_t)e3.x*32 + lane31];
    unsigned u4 = h2p[(size_t)e4.x*32 + lane31];
    unsigned u5 = h2p[(size_t)e5.x*32 + lane31];
    unsigned u6 = h2p[(size_t)e6.x*32 + lane31];
    unsigned u7 = h2p[(size_t)e7.x*32 + lane31];
    float w0 = __int_as_float(e0.y), w1 = __int_as_float(e1.y);
    float w2 = __int_as_float(e2.y), w3 = __int_as_float(e3.y);
    float w4 = __int_as_float(e4.y), w5 = __int_as_float(e5.y);
    float w6 = __int_as_float(e6.y), w7 = __int_as_float(e7.y);
    a0 = fmaf(bf_lo(u0), w0, a0); a1 = fmaf(bf_hi(u0), w0, a1);
    a0 = fmaf(bf_lo(u1), w1, a0); a1 = fmaf(bf_hi(u1), w1, a1);
    a0 = fmaf(bf_lo(u2), w2, a0); a1 = fmaf(bf_hi(u2), w2, a1);
    a0 = fmaf(bf_lo(u3), w3, a0); a1 = fmaf(bf_hi(u3), w3, a1);
    a0 = fmaf(bf_lo(u4), w4, a0); a1 = fmaf(bf_hi(u4), w4, a1);
    a0 = fmaf(bf_lo(u5), w5, a0); a1 = fmaf(bf_hi(u5), w5, a1);
    a0 = fmaf(bf_lo(u6), w6, a0); a1 = fmaf(bf_hi(u6), w6, a1);
    a0 = fmaf(bf_lo(u7), w7, a0); a1 = fmaf(bf_hi(u7), w7, a1);
  }
  for (; i < cnt; ++i){
    int2 e = csre[o+i];
    unsigned u = h2p[(size_t)e.x*32 + lane31];
    float w = __int_as_float(e.y);
    a0 = fmaf(bf_lo(u), w, a0); a1 = fmaf(bf_hi(u), w, a1);
  }
  if (lane < 20){
    float2 bb = *(const float2*)(b2 + lane*2);
    a0 += bb.x;
    a1 += bb.y;
    *(float2*)(out + (size_t)n*40 + lane*2) = make_float2(a0, a1);
  }
}

// ---------------- launch ----------------
extern "C" void kernel_launch(void* const* d_in, const int* in_sizes, int n_in,
                              void* d_out, int out_size, void* d_ws, size_t ws_size,
                              hipStream_t stream){
  const float* x  = (const float*)d_in[0];
  const int*   ei = (const int*)  d_in[1];
  const float* W1 = (const float*)d_in[2];
  const float* b1 = (const float*)d_in[3];
  const float* W2 = (const float*)d_in[4];
  const float* b2 = (const float*)d_in[5];
  float* out = (float*)d_out;
  char* ws = (char*)d_ws;
  const int N = N_NODES, E = N_EDGES;
  const int* srcv = ei;
  const int* dstv = ei + E;

  // workspace layout (bytes); total ~81.4 MB
  int*   bcur2 = (int*)  (ws + 0);          // 196 ints (zeroed each call)
  int*   off   = (int*)  (ws + 8192);       // N ints
  int*   degi  = (int*)  (ws + 417792);     // N ints
  float* dii   = (float*)(ws + 827392);     // N floats
  unsigned short* W1T = (unsigned short*)(ws + 1236992);   // 128*128 u16 = 32 KB
  int2*  tmp   = (int2*) (ws + 1269760);    // 196*9216 int2 (14.45 MB)
  int2*  csre  = (int2*) (ws + 15720448);   // 196*9216 int2 (14.45 MB)
  unsigned short* h1u = (unsigned short*)(ws + 30171136);  // [N][128] u16 = 25.6 MB
  unsigned*       h1g = (unsigned*)      (ws + 30171136);  // same memory as u32 pairs
  unsigned short* h2p = (unsigned short*)(ws + 30171136);  // aliases h1 (dead after agg1)
  unsigned*       Bbg = (unsigned*)      (ws + 55771136);  // [N][64] u32 = 25.6 MB

  hipMemsetAsync(bcur2, 0, 8192, stream);
  k_wt<<<64, 256, 0, stream>>>(W1, W1T);

  // k_B: F2 append (fixed bucket regions) + MFMA gemm1
  k_B<<<FB + G1B, 256, 0, stream>>>(x, W1T, h1u, srcv, dstv, bcur2, tmp, N, E);
  // degree histogram + prefix
  k_hist<<<NBUCK, 512, 0, stream>>>(tmp, bcur2, degi, off, dii, N);
  // counting sort -> final CSR
  k_csort<<<NBUCK, 1024, 0, stream>>>(tmp, csre, off, bcur2, dii, N);

  k_agg1 <<<N/4, 256, 0, stream>>>(h1g, Bbg, csre, off, degi, dii, b1, N);
  k_gemm2<<<(N + 63)/64, 256, 0, stream>>>(Bbg, W2, h2p, N);
  k_agg2 <<<N/4, 256, 0, stream>>>((const unsigned*)h2p, out, csre, off, degi, dii, b2, N);
}

// Round 15
// 215.952 us; speedup vs baseline: 1.1214x; 1.0638x over previous
//
#include <hip/hip_runtime.h>

#define N_NODES 100000
#define N_EDGES 1600000
#define NBUCK 196            // ceil(N / 512)
#define G1B 1563             // gemm1 blocks (64 rows each)
#define FB 391               // F2 blocks (x 4096 edges)
#define FEDGE 4096
#define BCAP 9216            // per-bucket capacity: mean 8192, sigma~90 -> 11 sigma

typedef __attribute__((ext_vector_type(8))) short short8v;   // 8 bf16 (4 VGPRs)
typedef __attribute__((ext_vector_type(4))) float f32x4;

// ---------------- bf16 helpers ----------------
__device__ __forceinline__ unsigned pack_bf16(float a, float b){
  unsigned ua = __float_as_uint(a), ub = __float_as_uint(b);
  ua = ua + 0x7fffu + ((ua >> 16) & 1u);          // RNE
  ub = ub + 0x7fffu + ((ub >> 16) & 1u);
  return (ua >> 16) | (ub & 0xffff0000u);
}
__device__ __forceinline__ unsigned short bf16_of(float a){
  unsigned ua = __float_as_uint(a);
  ua = ua + 0x7fffu + ((ua >> 16) & 1u);
  return (unsigned short)(ua >> 16);
}
__device__ __forceinline__ float bf_lo(unsigned u){ return __uint_as_float(u << 16); }
__device__ __forceinline__ float bf_hi(unsigned u){ return __uint_as_float(u & 0xffff0000u); }

// ---------------- threefry2x32 (JAX partitionable) dropout mask ------------
__device__ __forceinline__ unsigned tf_rotl(unsigned x, int r){ return (x<<r)|(x>>(32-r)); }

__device__ __forceinline__ unsigned dropout_keep(unsigned e){
  unsigned x0 = 0u, x1 = e;
  const unsigned k0 = 0u, k1v = 42u;
  const unsigned k2 = 0x1BD11BDAu ^ k0 ^ k1v;
#define TF_R(r) { x0 += x1; x1 = tf_rotl(x1,(r)); x1 ^= x0; }
  x0 += k0; x1 += k1v;
  TF_R(13) TF_R(15) TF_R(26) TF_R(6)
  x0 += k1v; x1 += k2 + 1u;
  TF_R(17) TF_R(29) TF_R(16) TF_R(24)
  x0 += k2; x1 += k0 + 2u;
  TF_R(13) TF_R(15) TF_R(26) TF_R(6)
  x0 += k0; x1 += k1v + 3u;
  TF_R(17) TF_R(29) TF_R(16) TF_R(24)
  x0 += k1v; x1 += k2 + 4u;
  TF_R(13) TF_R(15) TF_R(26) TF_R(6)
  x0 += k2; x1 += k0 + 5u;
#undef TF_R
  return (x0 ^ x1) >> 31;
}

// ---------------- k_init: bcur2=0, W1T(bf16), W2T48(bf16, zero-padded) ------
__global__ void k_init(const float* __restrict__ W1, const float* __restrict__ W2,
                       unsigned short* __restrict__ W1T, unsigned short* __restrict__ W2T48,
                       int* __restrict__ bcur2){
  int b = blockIdx.x, t = threadIdx.x;
  if (b < 64){
    int idx = b*256 + t;           // 16384 = 128*128
    int k = idx >> 7, n = idx & 127;
    W1T[n*128 + k] = bf16_of(W1[idx]);
  } else {
    if (t < NBUCK) bcur2[t] = 0;
    for (int i = t; i < 48*128; i += 256){
      int c = i >> 7, k = i & 127;
      W2T48[c*128 + k] = (c < 40) ? bf16_of(W2[k*40 + c]) : (unsigned short)0;
    }
  }
}

// ---------------- k_B: F2 bucket-append (packed u32) + MFMA gemm1 -----------
// F2: 391 blocks x 4096 edges -> bucket runs of packed (dloc<<17)|src (u32:
// half the scatter bytes of int2). gemm: 1563 blocks x 64 rows, bf16 MFMA,
// no LDS; A from global x (inline convert), B from L2-resident W1T.
__launch_bounds__(256)
__global__ void k_B(const float* __restrict__ x, const unsigned short* __restrict__ W1T,
                    unsigned short* __restrict__ h1u,
                    const int* __restrict__ src, const int* __restrict__ dst,
                    int* __restrict__ bcur2, unsigned* __restrict__ tmp, int N, int E){
  __shared__ int hist[NBUCK];
  int t = threadIdx.x;
  if (blockIdx.x < FB){
    int fb = blockIdx.x;
    for (int i = t; i < NBUCK; i += 256) hist[i] = 0;
    __syncthreads();
    int e0 = fb*FEDGE;
    #pragma unroll 4
    for (int j = 0; j < FEDGE/256; j++){
      int e = e0 + t + j*256;
      if (e < E) atomicAdd(&hist[dst[e] >> 9], 1);
    }
    __syncthreads();
    if (t < NBUCK){
      int c = hist[t];
      if (c > 0) hist[t] = t*BCAP + atomicAdd(&bcur2[t], c);
    }
    __syncthreads();
    #pragma unroll 4
    for (int j = 0; j < FEDGE/256; j++){
      int e = e0 + t + j*256;
      if (e < E){
        int d = dst[e], s = src[e];
        int p = atomicAdd(&hist[d >> 9], 1);
        tmp[p] = ((unsigned)(d & 511) << 17) | (unsigned)s;
      }
    }
    return;
  }
  // ---------- MFMA gemm role ----------
  int gb = blockIdx.x - FB;
  if (gb >= G1B) return;
  int w = t >> 6, l = t & 63;
  int lo = l & 15, hi = l >> 4;
  int rowA = gb*64 + w*16 + lo;
  int rA = (rowA < N) ? rowA : (N-1);
  const float4* xr = (const float4*)(x + (size_t)rA*128);

  short8v a[4];
  #pragma unroll
  for (int kk = 0; kk < 4; kk++){
    float4 f0 = xr[kk*8 + 2*hi];
    float4 f1 = xr[kk*8 + 2*hi + 1];
    union { short8v v; unsigned u[4]; } A;
    A.u[0] = pack_bf16(f0.x, f0.y);
    A.u[1] = pack_bf16(f0.z, f0.w);
    A.u[2] = pack_bf16(f1.x, f1.y);
    A.u[3] = pack_bf16(f1.z, f1.w);
    a[kk] = A.v;
  }
  int rowC0 = gb*64 + w*16 + hi*4;
  #pragma unroll
  for (int tt = 0; tt < 8; tt++){
    int n0 = tt*16;
    const uint4* brow = (const uint4*)(W1T + (n0 + lo)*128);
    f32x4 acc = {0.f, 0.f, 0.f, 0.f};
    #pragma unroll
    for (int kk = 0; kk < 4; kk++){
      union { short8v v; uint4 q; } B;
      B.q = brow[kk*4 + hi];
      acc = __builtin_amdgcn_mfma_f32_16x16x32_bf16(a[kk], B.v, acc, 0, 0, 0);
    }
    int colC = n0 + lo;
    #pragma unroll
    for (int r = 0; r < 4; r++){
      int rc = rowC0 + r;
      if (rc < N) h1u[(size_t)rc*128 + colC] = bf16_of(acc[r]);
    }
  }
}

// ---------------- k_sort: fused per-bucket hist + prefix + counting sort ----
// All bucket-local (csre stores src only; no cross-bucket dii needed).
__launch_bounds__(1024)
__global__ void k_sort(const unsigned* __restrict__ tmp, const int* __restrict__ bcur2,
                       int* __restrict__ degi, int* __restrict__ off,
                       float* __restrict__ dii, unsigned* __restrict__ csr, int N){
  __shared__ int cur[512];
  __shared__ int wtot[8];
  int b = blockIdx.x, t = threadIdx.x;
  if (t < 512) cur[t] = 0;
  __syncthreads();
  int m = bcur2[b];
  int base = b*BCAP;
  int node0 = b << 9;
  for (int i = t; i < m; i += 1024)
    atomicAdd(&cur[tmp[base + i] >> 17], 1);
  __syncthreads();
  int v = 0, excl = 0;
  if (t < 512){
    v = cur[t];
    int lane = t & 63, w = t >> 6;
    int incl = v;
    for (int d = 1; d < 64; d <<= 1){
      int y = __shfl_up(incl, d);
      if (lane >= d) incl += y;
    }
    if (lane == 63) wtot[w] = incl;
    __syncthreads();
    int wb = 0;
    for (int i = 0; i < w; i++) wb += wtot[i];
    excl = wb + incl - v;
    int n = node0 + t;
    if (n < N){
      degi[n] = v;
      off[n]  = base + excl;
      dii[n]  = rsqrtf((float)(v + 1));
    }
  } else {
    __syncthreads();
  }
  __syncthreads();
  if (t < 512) cur[t] = base + excl;
  __syncthreads();
  for (int i = t; i < m; i += 1024){
    unsigned e = tmp[base + i];
    int dloc = e >> 17;
    int p = atomicAdd(&cur[dloc], 1);
    csr[p] = e & 0x1FFFFu;
  }
}

// ---------------- agg1: Bbg(bf16) = dropout(relu(segsum(h1[src]*w)+b1)) -----
// wave per dst; src indices scalar (s_load); w = dii[s]*din via dependent
// s_load (dii L2-resident); full-wave 64-lane u32 gathers; 8-edge unroll.
__launch_bounds__(256)
__global__ void k_agg1(const unsigned* __restrict__ h1g, unsigned* __restrict__ Bbg,
                       const unsigned* __restrict__ csr, const int* __restrict__ off,
                       const int* __restrict__ degi, const float* __restrict__ dii,
                       const float* __restrict__ b1, int N){
  int n = blockIdx.x*4 + (threadIdx.x >> 6);
  int lane = threadIdx.x & 63;
  if (n >= N) return;
  n = __builtin_amdgcn_readfirstlane(n);
  float din = dii[n];
  float s2 = din*din;
  unsigned su = h1g[(size_t)n*64 + lane];
  float a0 = bf_lo(su)*s2, a1 = bf_hi(su)*s2;
  int o = off[n], cnt = degi[n];
  int i = 0;
  for (; i + 8 <= cnt; i += 8){
    unsigned s0 = csr[o+i+0], s1 = csr[o+i+1], s2i = csr[o+i+2], s3 = csr[o+i+3];
    unsigned s4 = csr[o+i+4], s5 = csr[o+i+5], s6 = csr[o+i+6], s7 = csr[o+i+7];
    float w0 = dii[s0]*din, w1 = dii[s1]*din, w2 = dii[s2i]*din, w3 = dii[s3]*din;
    float w4 = dii[s4]*din, w5 = dii[s5]*din, w6 = dii[s6]*din, w7 = dii[s7]*din;
    unsigned u0 = h1g[(size_t)s0*64 + lane];
    unsigned u1 = h1g[(size_t)s1*64 + lane];
    unsigned u2 = h1g[(size_t)s2i*64 + lane];
    unsigned u3 = h1g[(size_t)s3*64 + lane];
    unsigned u4 = h1g[(size_t)s4*64 + lane];
    unsigned u5 = h1g[(size_t)s5*64 + lane];
    unsigned u6 = h1g[(size_t)s6*64 + lane];
    unsigned u7 = h1g[(size_t)s7*64 + lane];
    a0 = fmaf(bf_lo(u0), w0, a0); a1 = fmaf(bf_hi(u0), w0, a1);
    a0 = fmaf(bf_lo(u1), w1, a0); a1 = fmaf(bf_hi(u1), w1, a1);
    a0 = fmaf(bf_lo(u2), w2, a0); a1 = fmaf(bf_hi(u2), w2, a1);
    a0 = fmaf(bf_lo(u3), w3, a0); a1 = fmaf(bf_hi(u3), w3, a1);
    a0 = fmaf(bf_lo(u4), w4, a0); a1 = fmaf(bf_hi(u4), w4, a1);
    a0 = fmaf(bf_lo(u5), w5, a0); a1 = fmaf(bf_hi(u5), w5, a1);
    a0 = fmaf(bf_lo(u6), w6, a0); a1 = fmaf(bf_hi(u6), w6, a1);
    a0 = fmaf(bf_lo(u7), w7, a0); a1 = fmaf(bf_hi(u7), w7, a1);
  }
  for (; i < cnt; ++i){
    unsigned s = csr[o+i];
    float w = dii[s]*din;
    unsigned u = h1g[(size_t)s*64 + lane];
    a0 = fmaf(bf_lo(u), w, a0); a1 = fmaf(bf_hi(u), w, a1);
  }
  float2 bb = *(const float2*)(b1 + lane*2);
  a0 = fmaxf(a0 + bb.x, 0.f);
  a1 = fmaxf(a1 + bb.y, 0.f);
  unsigned e0i = (unsigned)n*128u + (unsigned)lane*2u;
  a0 = dropout_keep(e0i)      ? a0*2.f : 0.f;
  a1 = dropout_keep(e0i + 1u) ? a1*2.f : 0.f;
  Bbg[(size_t)n*64 + lane] = pack_bf16(a0, a1);
}

// ---------------- GEMM2 (MFMA): h2p[N][64] = B @ W2T48^T --------------------
// Bbg rows are ready-made bf16 A-fragments (row-major 128 bf16). 3 col-tiles
// (48 cols, 40 valid + 8 zero). No LDS; W2T48 12KB L2-broadcast.
__launch_bounds__(256)
__global__ void k_gemm2(const unsigned* __restrict__ Bbg, const unsigned short* __restrict__ W2T48,
                        unsigned short* __restrict__ h2p, int N){
  int t = threadIdx.x;
  int w = t >> 6, l = t & 63;
  int lo = l & 15, hi = l >> 4;
  int rowA = blockIdx.x*64 + w*16 + lo;
  int rA = (rowA < N) ? rowA : (N-1);
  const uint4* ar = (const uint4*)(Bbg + (size_t)rA*64);

  short8v a[4];
  #pragma unroll
  for (int kk = 0; kk < 4; kk++){
    union { short8v v; uint4 q; } A;
    A.q = ar[kk*4 + hi];
    a[kk] = A.v;
  }
  int rowC0 = blockIdx.x*64 + w*16 + hi*4;
  #pragma unroll
  for (int tt = 0; tt < 3; tt++){
    int n0 = tt*16;
    const uint4* brow = (const uint4*)(W2T48 + (n0 + lo)*128);
    f32x4 acc = {0.f, 0.f, 0.f, 0.f};
    #pragma unroll
    for (int kk = 0; kk < 4; kk++){
      union { short8v v; uint4 q; } B;
      B.q = brow[kk*4 + hi];
      acc = __builtin_amdgcn_mfma_f32_16x16x32_bf16(a[kk], B.v, acc, 0, 0, 0);
    }
    int colC = n0 + lo;
    #pragma unroll
    for (int r = 0; r < 4; r++){
      int rc = rowC0 + r;
      if (rc < N) h2p[(size_t)rc*64 + colC] = bf16_of(acc[r]);
    }
  }
}

// ---------------- agg2: out = segsum(h2[src]*w) + b2 ------------------------
// agg1's shape on padded [N][32]-u32 rows; scalar src + dependent dii s_load.
__launch_bounds__(256)
__global__ void k_agg2(const unsigned* __restrict__ h2p, float* __restrict__ out,
                       const unsigned* __restrict__ csr, const int* __restrict__ off,
                       const int* __restrict__ degi, const float* __restrict__ dii,
                       const float* __restrict__ b2, int N){
  int n = blockIdx.x*4 + (threadIdx.x >> 6);
  int lane31 = threadIdx.x & 31;
  int lane   = threadIdx.x & 63;
  if (n >= N) return;
  n = __builtin_amdgcn_readfirstlane(n);
  float din = dii[n];
  float sq = din*din;
  unsigned su = h2p[(size_t)n*32 + lane31];
  float a0 = bf_lo(su)*sq, a1 = bf_hi(su)*sq;
  int o = off[n], cnt = degi[n];
  int i = 0;
  for (; i + 8 <= cnt; i += 8){
    unsigned s0 = csr[o+i+0], s1 = csr[o+i+1], s2i = csr[o+i+2], s3 = csr[o+i+3];
    unsigned s4 = csr[o+i+4], s5 = csr[o+i+5], s6 = csr[o+i+6], s7 = csr[o+i+7];
    float w0 = dii[s0]*din, w1 = dii[s1]*din, w2 = dii[s2i]*din, w3 = dii[s3]*din;
    float w4 = dii[s4]*din, w5 = dii[s5]*din, w6 = dii[s6]*din, w7 = dii[s7]*din;
    unsigned u0 = h2p[(size_t)s0*32 + lane31];
    unsigned u1 = h2p[(size_t)s1*32 + lane31];
    unsigned u2 = h2p[(size_t)s2i*32 + lane31];
    unsigned u3 = h2p[(size_t)s3*32 + lane31];
    unsigned u4 = h2p[(size_t)s4*32 + lane31];
    unsigned u5 = h2p[(size_t)s5*32 + lane31];
    unsigned u6 = h2p[(size_t)s6*32 + lane31];
    unsigned u7 = h2p[(size_t)s7*32 + lane31];
    a0 = fmaf(bf_lo(u0), w0, a0); a1 = fmaf(bf_hi(u0), w0, a1);
    a0 = fmaf(bf_lo(u1), w1, a0); a1 = fmaf(bf_hi(u1), w1, a1);
    a0 = fmaf(bf_lo(u2), w2, a0); a1 = fmaf(bf_hi(u2), w2, a1);
    a0 = fmaf(bf_lo(u3), w3, a0); a1 = fmaf(bf_hi(u3), w3, a1);
    a0 = fmaf(bf_lo(u4), w4, a0); a1 = fmaf(bf_hi(u4), w4, a1);
    a0 = fmaf(bf_lo(u5), w5, a0); a1 = fmaf(bf_hi(u5), w5, a1);
    a0 = fmaf(bf_lo(u6), w6, a0); a1 = fmaf(bf_hi(u6), w6, a1);
    a0 = fmaf(bf_lo(u7), w7, a0); a1 = fmaf(bf_hi(u7), w7, a1);
  }
  for (; i < cnt; ++i){
    unsigned s = csr[o+i];
    float w = dii[s]*din;
    unsigned u = h2p[(size_t)s*32 + lane31];
    a0 = fmaf(bf_lo(u), w, a0); a1 = fmaf(bf_hi(u), w, a1);
  }
  if (lane < 20){
    float2 bb = *(const float2*)(b2 + lane*2);
    a0 += bb.x;
    a1 += bb.y;
    *(float2*)(out + (size_t)n*40 + lane*2) = make_float2(a0, a1);
  }
}

// ---------------- launch ----------------
extern "C" void kernel_launch(void* const* d_in, const int* in_sizes, int n_in,
                              void* d_out, int out_size, void* d_ws, size_t ws_size,
                              hipStream_t stream){
  const float* x  = (const float*)d_in[0];
  const int*   ei = (const int*)  d_in[1];
  const float* W1 = (const float*)d_in[2];
  const float* b1 = (const float*)d_in[3];
  const float* W2 = (const float*)d_in[4];
  const float* b2 = (const float*)d_in[5];
  float* out = (float*)d_out;
  char* ws = (char*)d_ws;
  const int N = N_NODES, E = N_EDGES;
  const int* srcv = ei;
  const int* dstv = ei + E;

  // workspace layout (bytes); total ~76 MB
  int*   bcur2 = (int*)  (ws + 0);          // 196 ints (zeroed in k_init)
  int*   off   = (int*)  (ws + 8192);       // N ints
  int*   degi  = (int*)  (ws + 417792);     // N ints
  float* dii   = (float*)(ws + 827392);     // N floats
  unsigned short* W1T   = (unsigned short*)(ws + 1236992);  // 32 KB
  unsigned short* W2T48 = (unsigned short*)(ws + 1269760);  // 12 KB
  unsigned* tmp = (unsigned*)(ws + 1290240);  // 196*9216 u32 (7.2 MB) packed edges
  unsigned* csr = (unsigned*)(ws + 8519680);  // 196*9216 u32 (7.2 MB) src-only CSR
  unsigned short* h1u = (unsigned short*)(ws + 16777216);  // [N][128] u16 = 25.6 MB
  unsigned*       h1g = (unsigned*)      (ws + 16777216);  // same memory (u32 pairs)
  unsigned short* h2p = (unsigned short*)(ws + 16777216);  // aliases h1 (dead after agg1)
  unsigned*       Bbg = (unsigned*)      (ws + 50331648);  // [N][64] u32 = 25.6 MB

  k_init<<<65, 256, 0, stream>>>(W1, W2, W1T, W2T48, bcur2);
  // F2 bucket-append (packed u32, fixed regions) + MFMA gemm1
  k_B<<<FB + G1B, 256, 0, stream>>>(x, W1T, h1u, srcv, dstv, bcur2, tmp, N, E);
  // fused per-bucket histogram + prefix + counting sort
  k_sort<<<NBUCK, 1024, 0, stream>>>(tmp, bcur2, degi, off, dii, csr, N);

  k_agg1 <<<N/4, 256, 0, stream>>>(h1g, Bbg, csr, off, degi, dii, b1, N);
  k_gemm2<<<(N + 63)/64, 256, 0, stream>>>(Bbg, W2T48, h2p, N);
  k_agg2 <<<N/4, 256, 0, stream>>>((const unsigned*)h2p, out, csr, off, degi, dii, b2, N);
}

// Round 16
// 210.451 us; speedup vs baseline: 1.1508x; 1.0261x over previous
//
#include <hip/hip_runtime.h>

#define N_NODES 100000
#define N_EDGES 1600000
#define NBUCK 196            // ceil(N / 512)
#define G1B 1563             // gemm1 blocks (64 rows each)
#define FB 391               // F2 blocks (x 4096 edges)
#define FEDGE 4096
#define BCAP 9216            // per-bucket capacity: mean 8192, sigma~90 -> 11 sigma

typedef __attribute__((ext_vector_type(8))) short short8v;   // 8 bf16 (4 VGPRs)
typedef __attribute__((ext_vector_type(4))) float f32x4;

// ---------------- bf16 helpers ----------------
__device__ __forceinline__ unsigned pack_bf16(float a, float b){
  unsigned ua = __float_as_uint(a), ub = __float_as_uint(b);
  ua = ua + 0x7fffu + ((ua >> 16) & 1u);          // RNE
  ub = ub + 0x7fffu + ((ub >> 16) & 1u);
  return (ua >> 16) | (ub & 0xffff0000u);
}
__device__ __forceinline__ unsigned short bf16_of(float a){
  unsigned ua = __float_as_uint(a);
  ua = ua + 0x7fffu + ((ua >> 16) & 1u);
  return (unsigned short)(ua >> 16);
}
__device__ __forceinline__ float bf_lo(unsigned u){ return __uint_as_float(u << 16); }
__device__ __forceinline__ float bf_hi(unsigned u){ return __uint_as_float(u & 0xffff0000u); }

// ---------------- threefry2x32 (JAX partitionable) dropout mask ------------
__device__ __forceinline__ unsigned tf_rotl(unsigned x, int r){ return (x<<r)|(x>>(32-r)); }

__device__ __forceinline__ unsigned dropout_keep(unsigned e){
  unsigned x0 = 0u, x1 = e;
  const unsigned k0 = 0u, k1v = 42u;
  const unsigned k2 = 0x1BD11BDAu ^ k0 ^ k1v;
#define TF_R(r) { x0 += x1; x1 = tf_rotl(x1,(r)); x1 ^= x0; }
  x0 += k0; x1 += k1v;
  TF_R(13) TF_R(15) TF_R(26) TF_R(6)
  x0 += k1v; x1 += k2 + 1u;
  TF_R(17) TF_R(29) TF_R(16) TF_R(24)
  x0 += k2; x1 += k0 + 2u;
  TF_R(13) TF_R(15) TF_R(26) TF_R(6)
  x0 += k0; x1 += k1v + 3u;
  TF_R(17) TF_R(29) TF_R(16) TF_R(24)
  x0 += k1v; x1 += k2 + 4u;
  TF_R(13) TF_R(15) TF_R(26) TF_R(6)
  x0 += k2; x1 += k0 + 5u;
#undef TF_R
  return (x0 ^ x1) >> 31;
}

// ---------------- k_init: bcur2=0, W1T(bf16), W2T48(bf16, zero-padded) ------
__global__ void k_init(const float* __restrict__ W1, const float* __restrict__ W2,
                       unsigned short* __restrict__ W1T, unsigned short* __restrict__ W2T48,
                       int* __restrict__ bcur2){
  int b = blockIdx.x, t = threadIdx.x;
  if (b < 64){
    int idx = b*256 + t;           // 16384 = 128*128
    int k = idx >> 7, n = idx & 127;
    W1T[n*128 + k] = bf16_of(W1[idx]);
  } else {
    if (t < NBUCK) bcur2[t] = 0;
    for (int i = t; i < 48*128; i += 256){
      int c = i >> 7, k = i & 127;
      W2T48[c*128 + k] = (c < 40) ? bf16_of(W2[k*40 + c]) : (unsigned short)0;
    }
  }
}

// ---------------- k_B: F2 bucket-append (packed u32) + MFMA gemm1 -----------
__launch_bounds__(256)
__global__ void k_B(const float* __restrict__ x, const unsigned short* __restrict__ W1T,
                    unsigned short* __restrict__ h1u,
                    const int* __restrict__ src, const int* __restrict__ dst,
                    int* __restrict__ bcur2, unsigned* __restrict__ tmp, int N, int E){
  __shared__ int hist[NBUCK];
  int t = threadIdx.x;
  if (blockIdx.x < FB){
    int fb = blockIdx.x;
    for (int i = t; i < NBUCK; i += 256) hist[i] = 0;
    __syncthreads();
    int e0 = fb*FEDGE;
    #pragma unroll 4
    for (int j = 0; j < FEDGE/256; j++){
      int e = e0 + t + j*256;
      if (e < E) atomicAdd(&hist[dst[e] >> 9], 1);
    }
    __syncthreads();
    if (t < NBUCK){
      int c = hist[t];
      if (c > 0) hist[t] = t*BCAP + atomicAdd(&bcur2[t], c);
    }
    __syncthreads();
    #pragma unroll 4
    for (int j = 0; j < FEDGE/256; j++){
      int e = e0 + t + j*256;
      if (e < E){
        int d = dst[e], s = src[e];
        int p = atomicAdd(&hist[d >> 9], 1);
        tmp[p] = ((unsigned)(d & 511) << 17) | (unsigned)s;
      }
    }
    return;
  }
  // ---------- MFMA gemm role ----------
  int gb = blockIdx.x - FB;
  if (gb >= G1B) return;
  int w = t >> 6, l = t & 63;
  int lo = l & 15, hi = l >> 4;
  int rowA = gb*64 + w*16 + lo;
  int rA = (rowA < N) ? rowA : (N-1);
  const float4* xr = (const float4*)(x + (size_t)rA*128);

  short8v a[4];
  #pragma unroll
  for (int kk = 0; kk < 4; kk++){
    float4 f0 = xr[kk*8 + 2*hi];
    float4 f1 = xr[kk*8 + 2*hi + 1];
    union { short8v v; unsigned u[4]; } A;
    A.u[0] = pack_bf16(f0.x, f0.y);
    A.u[1] = pack_bf16(f0.z, f0.w);
    A.u[2] = pack_bf16(f1.x, f1.y);
    A.u[3] = pack_bf16(f1.z, f1.w);
    a[kk] = A.v;
  }
  int rowC0 = gb*64 + w*16 + hi*4;
  #pragma unroll
  for (int tt = 0; tt < 8; tt++){
    int n0 = tt*16;
    const uint4* brow = (const uint4*)(W1T + (n0 + lo)*128);
    f32x4 acc = {0.f, 0.f, 0.f, 0.f};
    #pragma unroll
    for (int kk = 0; kk < 4; kk++){
      union { short8v v; uint4 q; } B;
      B.q = brow[kk*4 + hi];
      acc = __builtin_amdgcn_mfma_f32_16x16x32_bf16(a[kk], B.v, acc, 0, 0, 0);
    }
    int colC = n0 + lo;
    #pragma unroll
    for (int r = 0; r < 4; r++){
      int rc = rowC0 + r;
      if (rc < N) h1u[(size_t)rc*128 + colC] = bf16_of(acc[r]);
    }
  }
}

// ---------------- k_hist: per-bucket hist + prefix -> degi/off/dii ----------
__launch_bounds__(1024)
__global__ void k_hist(const unsigned* __restrict__ tmp, const int* __restrict__ bcur2,
                       int* __restrict__ degi, int* __restrict__ off,
                       float* __restrict__ dii, int N){
  __shared__ int cur[512];
  __shared__ int wtot[8];
  int b = blockIdx.x, t = threadIdx.x;
  if (t < 512) cur[t] = 0;
  __syncthreads();
  int m = bcur2[b];
  int base = b*BCAP;
  int node0 = b << 9;
  for (int i = t; i < m; i += 1024)
    atomicAdd(&cur[tmp[base + i] >> 17], 1);
  __syncthreads();
  if (t < 512){
    int v = cur[t];
    int lane = t & 63, w = t >> 6;
    int incl = v;
    for (int d = 1; d < 64; d <<= 1){
      int y = __shfl_up(incl, d);
      if (lane >= d) incl += y;
    }
    if (lane == 63) wtot[w] = incl;
    __syncthreads();
    int wb = 0;
    for (int i = 0; i < w; i++) wb += wtot[i];
    int excl = wb + incl - v;
    int n = node0 + t;
    if (n < N){
      degi[n] = v;
      off[n]  = base + excl;
      dii[n]  = rsqrtf((float)(v + 1));
    }
  }
}

// ---------------- k_csort: counting sort -> int2 csre (src, w) --------------
// per-lane edges; dii[s] gathered from L2-resident 400KB array; bucket-local
// scatter -> full-line evictions.
__launch_bounds__(1024)
__global__ void k_csort(const unsigned* __restrict__ tmp, int2* __restrict__ csre,
                        const int* __restrict__ off, const int* __restrict__ bcur2,
                        const float* __restrict__ dii, int N){
  __shared__ int   cur[512];
  __shared__ float dl[512];
  int b = blockIdx.x, t = threadIdx.x;
  int node0 = b << 9;
  if (t < 512){
    int n = node0 + t;
    cur[t] = (n < N) ? off[n] : 0;
    dl[t]  = (n < N) ? dii[n] : 0.f;
  }
  __syncthreads();
  int m = bcur2[b];
  int base = b*BCAP;
  for (int i = t; i < m; i += 1024){
    unsigned e = tmp[base + i];
    int dloc = e >> 17;
    int s = e & 0x1FFFFu;
    float w = dii[s] * dl[dloc];
    int p = atomicAdd(&cur[dloc], 1);
    csre[p] = make_int2(s, __float_as_int(w));
  }
}

// ---------------- agg1: Bbg(bf16) = dropout(relu(segsum(h1[src]*w)+b1)) -----
// R14-proven form: wave per dst; int2 edge records in SGPRs (s_load_dwordx);
// full-wave 64-lane u32 gathers; 8-edge unroll. 71us / FETCH 201MB.
__launch_bounds__(256)
__global__ void k_agg1(const unsigned* __restrict__ h1g, unsigned* __restrict__ Bbg,
                       const int2* __restrict__ csre, const int* __restrict__ off,
                       const int* __restrict__ degi, const float* __restrict__ dii,
                       const float* __restrict__ b1, int N){
  int n = blockIdx.x*4 + (threadIdx.x >> 6);
  int lane = threadIdx.x & 63;
  if (n >= N) return;
  n = __builtin_amdgcn_readfirstlane(n);
  float din = dii[n];
  float s2 = din*din;
  unsigned su = h1g[(size_t)n*64 + lane];
  float a0 = bf_lo(su)*s2, a1 = bf_hi(su)*s2;
  int o = off[n], cnt = degi[n];
  int i = 0;
  for (; i + 8 <= cnt; i += 8){
    int2 e0 = csre[o+i+0], e1 = csre[o+i+1], e2 = csre[o+i+2], e3 = csre[o+i+3];
    int2 e4 = csre[o+i+4], e5 = csre[o+i+5], e6 = csre[o+i+6], e7 = csre[o+i+7];
    unsigned u0 = h1g[(size_t)e0.x*64 + lane];
    unsigned u1 = h1g[(size_t)e1.x*64 + lane];
    unsigned u2 = h1g[(size_t)e2.x*64 + lane];
    unsigned u3 = h1g[(size_t)e3.x*64 + lane];
    unsigned u4 = h1g[(size_t)e4.x*64 + lane];
    unsigned u5 = h1g[(size_t)e5.x*64 + lane];
    unsigned u6 = h1g[(size_t)e6.x*64 + lane];
    unsigned u7 = h1g[(size_t)e7.x*64 + lane];
    float w0 = __int_as_float(e0.y), w1 = __int_as_float(e1.y);
    float w2 = __int_as_float(e2.y), w3 = __int_as_float(e3.y);
    float w4 = __int_as_float(e4.y), w5 = __int_as_float(e5.y);
    float w6 = __int_as_float(e6.y), w7 = __int_as_float(e7.y);
    a0 = fmaf(bf_lo(u0), w0, a0); a1 = fmaf(bf_hi(u0), w0, a1);
    a0 = fmaf(bf_lo(u1), w1, a0); a1 = fmaf(bf_hi(u1), w1, a1);
    a0 = fmaf(bf_lo(u2), w2, a0); a1 = fmaf(bf_hi(u2), w2, a1);
    a0 = fmaf(bf_lo(u3), w3, a0); a1 = fmaf(bf_hi(u3), w3, a1);
    a0 = fmaf(bf_lo(u4), w4, a0); a1 = fmaf(bf_hi(u4), w4, a1);
    a0 = fmaf(bf_lo(u5), w5, a0); a1 = fmaf(bf_hi(u5), w5, a1);
    a0 = fmaf(bf_lo(u6), w6, a0); a1 = fmaf(bf_hi(u6), w6, a1);
    a0 = fmaf(bf_lo(u7), w7, a0); a1 = fmaf(bf_hi(u7), w7, a1);
  }
  for (; i < cnt; ++i){
    int2 e = csre[o+i];
    unsigned u = h1g[(size_t)e.x*64 + lane];
    float w = __int_as_float(e.y);
    a0 = fmaf(bf_lo(u), w, a0); a1 = fmaf(bf_hi(u), w, a1);
  }
  float2 bb = *(const float2*)(b1 + lane*2);
  a0 = fmaxf(a0 + bb.x, 0.f);
  a1 = fmaxf(a1 + bb.y, 0.f);
  unsigned e0i = (unsigned)n*128u + (unsigned)lane*2u;
  a0 = dropout_keep(e0i)      ? a0*2.f : 0.f;
  a1 = dropout_keep(e0i + 1u) ? a1*2.f : 0.f;
  Bbg[(size_t)n*64 + lane] = pack_bf16(a0, a1);
}

// ---------------- GEMM2 (MFMA): h2p[N][64] = B @ W2T48^T --------------------
__launch_bounds__(256)
__global__ void k_gemm2(const unsigned* __restrict__ Bbg, const unsigned short* __restrict__ W2T48,
                        unsigned short* __restrict__ h2p, int N){
  int t = threadIdx.x;
  int w = t >> 6, l = t & 63;
  int lo = l & 15, hi = l >> 4;
  int rowA = blockIdx.x*64 + w*16 + lo;
  int rA = (rowA < N) ? rowA : (N-1);
  const uint4* ar = (const uint4*)(Bbg + (size_t)rA*64);

  short8v a[4];
  #pragma unroll
  for (int kk = 0; kk < 4; kk++){
    union { short8v v; uint4 q; } A;
    A.q = ar[kk*4 + hi];
    a[kk] = A.v;
  }
  int rowC0 = blockIdx.x*64 + w*16 + hi*4;
  #pragma unroll
  for (int tt = 0; tt < 3; tt++){
    int n0 = tt*16;
    const uint4* brow = (const uint4*)(W2T48 + (n0 + lo)*128);
    f32x4 acc = {0.f, 0.f, 0.f, 0.f};
    #pragma unroll
    for (int kk = 0; kk < 4; kk++){
      union { short8v v; uint4 q; } B;
      B.q = brow[kk*4 + hi];
      acc = __builtin_amdgcn_mfma_f32_16x16x32_bf16(a[kk], B.v, acc, 0, 0, 0);
    }
    int colC = n0 + lo;
    #pragma unroll
    for (int r = 0; r < 4; r++){
      int rc = rowC0 + r;
      if (rc < N) h2p[(size_t)rc*64 + colC] = bf16_of(acc[r]);
    }
  }
}

// ---------------- agg2: out = segsum(h2[src]*w) + b2 ------------------------
// R14-proven form on padded [N][32]-u32 rows; int2 edge records.
__launch_bounds__(256)
__global__ void k_agg2(const unsigned* __restrict__ h2p, float* __restrict__ out,
                       const int2* __restrict__ csre, const int* __restrict__ off,
                       const int* __restrict__ degi, const float* __restrict__ dii,
                       const float* __restrict__ b2, int N){
  int n = blockIdx.x*4 + (threadIdx.x >> 6);
  int lane31 = threadIdx.x & 31;
  int lane   = threadIdx.x & 63;
  if (n >= N) return;
  n = __builtin_amdgcn_readfirstlane(n);
  float din = dii[n];
  float sq = din*din;
  unsigned su = h2p[(size_t)n*32 + lane31];
  float a0 = bf_lo(su)*sq, a1 = bf_hi(su)*sq;
  int o = off[n], cnt = degi[n];
  int i = 0;
  for (; i + 8 <= cnt; i += 8){
    int2 e0 = csre[o+i+0], e1 = csre[o+i+1], e2 = csre[o+i+2], e3 = csre[o+i+3];
    int2 e4 = csre[o+i+4], e5 = csre[o+i+5], e6 = csre[o+i+6], e7 = csre[o+i+7];
    unsigned u0 = h2p[(size_t)e0.x*32 + lane31];
    unsigned u1 = h2p[(size_t)e1.x*32 + lane31];
    unsigned u2 = h2p[(size_t)e2.x*32 + lane31];
    unsigned u3 = h2p[(size_t)e3.x*32 + lane31];
    unsigned u4 = h2p[(size_t)e4.x*32 + lane31];
    unsigned u5 = h2p[(size_t)e5.x*32 + lane31];
    unsigned u6 = h2p[(size_t)e6.x*32 + lane31];
    unsigned u7 = h2p[(size_t)e7.x*32 + lane31];
    float w0 = __int_as_float(e0.y), w1 = __int_as_float(e1.y);
    float w2 = __int_as_float(e2.y), w3 = __int_as_float(e3.y);
    float w4 = __int_as_float(e4.y), w5 = __int_as_float(e5.y);
    float w6 = __int_as_float(e6.y), w7 = __int_as_float(e7.y);
    a0 = fmaf(bf_lo(u0), w0, a0); a1 = fmaf(bf_hi(u0), w0, a1);
    a0 = fmaf(bf_lo(u1), w1, a0); a1 = fmaf(bf_hi(u1), w1, a1);
    a0 = fmaf(bf_lo(u2), w2, a0); a1 = fmaf(bf_hi(u2), w2, a1);
    a0 = fmaf(bf_lo(u3), w3, a0); a1 = fmaf(bf_hi(u3), w3, a1);
    a0 = fmaf(bf_lo(u4), w4, a0); a1 = fmaf(bf_hi(u4), w4, a1);
    a0 = fmaf(bf_lo(u5), w5, a0); a1 = fmaf(bf_hi(u5), w5, a1);
    a0 = fmaf(bf_lo(u6), w6, a0); a1 = fmaf(bf_hi(u6), w6, a1);
    a0 = fmaf(bf_lo(u7), w7, a0); a1 = fmaf(bf_hi(u7), w7, a1);
  }
  for (; i < cnt; ++i){
    int2 e = csre[o+i];
    unsigned u = h2p[(size_t)e.x*32 + lane31];
    float w = __int_as_float(e.y);
    a0 = fmaf(bf_lo(u), w, a0); a1 = fmaf(bf_hi(u), w, a1);
  }
  if (lane < 20){
    float2 bb = *(const float2*)(b2 + lane*2);
    a0 += bb.x;
    a1 += bb.y;
    *(float2*)(out + (size_t)n*40 + lane*2) = make_float2(a0, a1);
  }
}

// ---------------- launch ----------------
extern "C" void kernel_launch(void* const* d_in, const int* in_sizes, int n_in,
                              void* d_out, int out_size, void* d_ws, size_t ws_size,
                              hipStream_t stream){
  const float* x  = (const float*)d_in[0];
  const int*   ei = (const int*)  d_in[1];
  const float* W1 = (const float*)d_in[2];
  const float* b1 = (const float*)d_in[3];
  const float* W2 = (const float*)d_in[4];
  const float* b2 = (const float*)d_in[5];
  float* out = (float*)d_out;
  char* ws = (char*)d_ws;
  const int N = N_NODES, E = N_EDGES;
  const int* srcv = ei;
  const int* dstv = ei + E;

  // workspace layout (bytes); total ~83 MB
  int*   bcur2 = (int*)  (ws + 0);          // 196 ints (zeroed in k_init)
  int*   off   = (int*)  (ws + 8192);       // N ints
  int*   degi  = (int*)  (ws + 417792);     // N ints
  float* dii   = (float*)(ws + 827392);     // N floats
  unsigned short* W1T   = (unsigned short*)(ws + 1236992);  // 32 KB
  unsigned short* W2T48 = (unsigned short*)(ws + 1269760);  // 12 KB
  unsigned* tmp = (unsigned*)(ws + 1290240);  // 196*9216 u32 (7.2 MB) packed edges
  int2*     csre= (int2*)   (ws + 8519680);   // 196*9216 int2 (14.5 MB) (src,w)
  unsigned short* h1u = (unsigned short*)(ws + 23068672);  // [N][128] u16 = 25.6 MB
  unsigned*       h1g = (unsigned*)      (ws + 23068672);  // same memory (u32 pairs)
  unsigned short* h2p = (unsigned short*)(ws + 23068672);  // aliases h1 (dead after agg1)
  unsigned*       Bbg = (unsigned*)      (ws + 56623104);  // [N][64] u32 = 25.6 MB

  k_init<<<65, 256, 0, stream>>>(W1, W2, W1T, W2T48, bcur2);
  // F2 bucket-append (packed u32, fixed regions) + MFMA gemm1
  k_B<<<FB + G1B, 256, 0, stream>>>(x, W1T, h1u, srcv, dstv, bcur2, tmp, N, E);
  // per-bucket histogram + prefix -> degi/off/dii
  k_hist<<<NBUCK, 1024, 0, stream>>>(tmp, bcur2, degi, off, dii, N);
  // counting sort -> int2 CSR (src, precomputed w)
  k_csort<<<NBUCK, 1024, 0, stream>>>(tmp, csre, off, bcur2, dii, N);

  k_agg1 <<<N/4, 256, 0, stream>>>(h1g, Bbg, csre, off, degi, dii, b1, N);
  k_gemm2<<<(N + 63)/64, 256, 0, stream>>>(Bbg, W2T48, h2p, N);
  k_agg2 <<<N/4, 256, 0, stream>>>((const unsigned*)h2p, out, csre, off, degi, dii, b2, N);
}